// Round 12
// baseline (182.323 us; speedup 1.0000x reference)
//
#include <hip/hip_runtime.h>
#include <math.h>

#define B_    32
#define C_    128
#define HW_   16384          // 128*128
#define NPIX  524288         // B_*HW_
#define EPSF  1e-5f

typedef float vfloat4 __attribute__((ext_vector_type(4)));  // native vec for nontemporal builtins

__device__ __forceinline__ float wave_sum(float v) {
#pragma unroll
    for (int off = 32; off > 0; off >>= 1) v += __shfl_down(v, off, 64);
    return v;
}

// Kernel 1 (R10 exact): per-pixel channel mean/max over C=128, channel loop
// split 2-way across wave halves, combine via shfl_xor 32. Emits feat[B][2][HW].
// BN1 stats as deterministic per-block partials pp[4][1024]; block 0 zeroes
// the BN2 accumulators for k_conv.
__global__ __launch_bounds__(256) void k_reduce(const float* __restrict__ x,
                                                float* __restrict__ feat,
                                                float* __restrict__ pp,
                                                float* __restrict__ bn2) {
    if (blockIdx.x == 0 && threadIdx.x < 2) bn2[threadIdx.x] = 0.f;  // ws not re-poisoned; zero every call

    int lane = threadIdx.x & 63, wid = threadIdx.x >> 6;
    int pg   = (blockIdx.x * 4 + wid) * 32 + (lane & 31);  // float4-pixel group, 131072 total
    int b    = pg >> 12;
    int hw   = (pg & 4095) << 2;
    int ch0  = (lane >> 5) * 64;                           // 0 or 64

    const float4* xp = reinterpret_cast<const float4*>(
        x + (size_t)b * C_ * HW_ + (size_t)ch0 * HW_ + hw);
    float4 s = make_float4(0.f, 0.f, 0.f, 0.f);
    float4 m = make_float4(-INFINITY, -INFINITY, -INFINITY, -INFINITY);
#pragma unroll 8
    for (int c = 0; c < 64; ++c) {
        float4 v = xp[(size_t)c * (HW_ / 4)];
        s.x += v.x; s.y += v.y; s.z += v.z; s.w += v.w;
        m.x = fmaxf(m.x, v.x); m.y = fmaxf(m.y, v.y);
        m.z = fmaxf(m.z, v.z); m.w = fmaxf(m.w, v.w);
    }
    s.x += __shfl_xor(s.x, 32, 64); s.y += __shfl_xor(s.y, 32, 64);
    s.z += __shfl_xor(s.z, 32, 64); s.w += __shfl_xor(s.w, 32, 64);
    m.x = fmaxf(m.x, __shfl_xor(m.x, 32, 64)); m.y = fmaxf(m.y, __shfl_xor(m.y, 32, 64));
    m.z = fmaxf(m.z, __shfl_xor(m.z, 32, 64)); m.w = fmaxf(m.w, __shfl_xor(m.w, 32, 64));

    const float inv = 1.0f / 128.0f;
    float4 a = make_float4(s.x * inv, s.y * inv, s.z * inv, s.w * inv);
    float* fb = feat + (size_t)b * 2 * HW_ + hw;
    if (lane < 32) *reinterpret_cast<float4*>(fb)       = a;   // avg plane
    else           *reinterpret_cast<float4*>(fb + HW_) = m;   // max plane

    float vals[4];
    vals[0] = a.x + a.y + a.z + a.w;
    vals[1] = a.x*a.x + a.y*a.y + a.z*a.z + a.w*a.w;
    vals[2] = m.x + m.y + m.z + m.w;
    vals[3] = m.x*m.x + m.y*m.y + m.z*m.z + m.w*m.w;

    __shared__ float red[4];
#pragma unroll
    for (int i = 0; i < 4; ++i) {        // halves duplicate -> 0.5x
        float v = wave_sum(vals[i]);
        if (lane == 0) red[wid] = v;
        __syncthreads();
        if (threadIdx.x == 0)
            pp[i * 1024 + blockIdx.x] = 0.5f * (red[0] + red[1] + red[2] + red[3]);
        __syncthreads();
    }
}

// Kernel 2 (R10 exact): prologue reduces the 4x1024 BN1 partials per block,
// then BN1-affine-fused 7x7x2 conv (OOB = 0 post-BN), 4 output pixels/thread
// with row-reuse. BN2 stats via atomics into bn2[2].
__global__ __launch_bounds__(256) void k_conv(const float* __restrict__ feat,
                                              const float* __restrict__ cw,
                                              const float* __restrict__ g1,
                                              const float* __restrict__ be1,
                                              const float* __restrict__ pp,
                                              float* __restrict__ convout,
                                              float* __restrict__ bn2) {
    __shared__ float w_s[98];
    __shared__ float sc_s[2], sh_s[2];
    __shared__ float red4[4][4];
    int lane = threadIdx.x & 63, wid = threadIdx.x >> 6;

    if (threadIdx.x < 98) w_s[threadIdx.x] = cw[threadIdx.x];
#pragma unroll
    for (int i = 0; i < 4; ++i) {
        const float* p = pp + i * 1024 + threadIdx.x;
        float a = p[0] + p[256] + p[512] + p[768];
        a = wave_sum(a);
        if (lane == 0) red4[i][wid] = a;
    }
    __syncthreads();
    if (threadIdx.x < 2) {
        const float invn = 1.0f / (float)NPIX;
        int c = threadIdx.x;
        float S = red4[2*c][0] + red4[2*c][1] + red4[2*c][2] + red4[2*c][3];
        float Q = red4[2*c+1][0] + red4[2*c+1][1] + red4[2*c+1][2] + red4[2*c+1][3];
        float mean = S * invn;
        float var  = Q * invn - mean * mean;
        float sc   = g1[c] / sqrtf(var + EPSF);
        sc_s[c] = sc;
        sh_s[c] = be1[c] - mean * sc;
    }
    __syncthreads();

    int t  = blockIdx.x * 256 + threadIdx.x;   // 131072 threads, 4 pixels each
    int b  = t >> 12;
    int pg = t & 4095;
    int h  = pg >> 5;
    int w4 = (pg & 31) << 2;                   // output col base (0,4,...,124)
    const float* fb = feat + (size_t)b * 2 * HW_;

    float acc0 = 0.f, acc1 = 0.f, acc2 = 0.f, acc3 = 0.f;
#pragma unroll
    for (int c = 0; c < 2; ++c) {
        float sc = sc_s[c], sh = sh_s[c];
        const float* fc = fb + c * HW_;
#pragma unroll
        for (int kh = 0; kh < 7; ++kh) {
            int hh = h + kh - 3;
            if ((unsigned)hh >= 128u) continue;
            const float* row = fc + hh * 128;
            float v[10];
#pragma unroll
            for (int i = 0; i < 10; ++i) {
                int ww = w4 - 3 + i;
                v[i] = ((unsigned)ww < 128u) ? row[ww] * sc + sh : 0.f;
            }
#pragma unroll
            for (int kw = 0; kw < 7; ++kw) {
                float wt = w_s[c * 49 + kh * 7 + kw];
                acc0 += v[kw]     * wt;
                acc1 += v[kw + 1] * wt;
                acc2 += v[kw + 2] * wt;
                acc3 += v[kw + 3] * wt;
            }
        }
    }
    *reinterpret_cast<float4*>(convout + (size_t)b * HW_ + h * 128 + w4) =
        make_float4(acc0, acc1, acc2, acc3);

    __shared__ float red[4];
    float v = wave_sum(acc0 + acc1 + acc2 + acc3);
    if (lane == 0) red[wid] = v;
    __syncthreads();
    if (threadIdx.x == 0) atomicAdd(bn2 + 0, red[0] + red[1] + red[2] + red[3]);
    __syncthreads();
    v = wave_sum(acc0*acc0 + acc1*acc1 + acc2*acc2 + acc3*acc3);
    if (lane == 0) red[wid] = v;
    __syncthreads();
    if (threadIdx.x == 0) atomicAdd(bn2 + 1, red[0] + red[1] + red[2] + red[3]);
}

// Kernel 3: att = sigmoid(BN2(conv)); out = att * x. CHANGE vs R11: each
// thread handles 2 ADJACENT float4s x 4 channels (clo,+32,+64,+96) -> wave
// footprint 2 KB contiguous per plane (was 1 KB), 8 independent nt-loads in
// flight per thread, one convout pair + 8 sigmoids serve 8 output quads.
// Reversed block order retained.
__global__ __launch_bounds__(256) void k_apply(const float* __restrict__ x,
                                               const float* __restrict__ convout,
                                               const float* __restrict__ g2,
                                               const float* __restrict__ be2,
                                               const float* __restrict__ bn2,
                                               float* __restrict__ out) {
    int t   = (gridDim.x - 1 - blockIdx.x) * 256 + threadIdx.x;  // 2,097,152 threads
    int hw8 = (t & 2047) << 3;           // 8-float group within the HW plane
    int clo = (t >> 11) & 31;
    int b   = t >> 16;

    const float invn = 1.0f / (float)NPIX;
    float mean = bn2[0] * invn;
    float var  = bn2[1] * invn - mean * mean;
    float s    = g2[0] / sqrtf(var + EPSF);
    float sh   = be2[0] - mean * s;

    const float* cvp = convout + (size_t)b * HW_ + hw8;
    float4 cv0 = *reinterpret_cast<const float4*>(cvp);
    float4 cv1 = *reinterpret_cast<const float4*>(cvp + 4);
    float att[8];
    att[0] = 1.f / (1.f + __expf(-(cv0.x * s + sh)));
    att[1] = 1.f / (1.f + __expf(-(cv0.y * s + sh)));
    att[2] = 1.f / (1.f + __expf(-(cv0.z * s + sh)));
    att[3] = 1.f / (1.f + __expf(-(cv0.w * s + sh)));
    att[4] = 1.f / (1.f + __expf(-(cv1.x * s + sh)));
    att[5] = 1.f / (1.f + __expf(-(cv1.y * s + sh)));
    att[6] = 1.f / (1.f + __expf(-(cv1.z * s + sh)));
    att[7] = 1.f / (1.f + __expf(-(cv1.w * s + sh)));

    size_t xbase = ((size_t)(b * 128 + clo)) * HW_ + hw8;
    const size_t cstep = (size_t)32 * HW_;

    vfloat4 xv[8];
#pragma unroll
    for (int k = 0; k < 4; ++k) {
        xv[2*k]   = __builtin_nontemporal_load(
            reinterpret_cast<const vfloat4*>(x + xbase + k * cstep));
        xv[2*k+1] = __builtin_nontemporal_load(
            reinterpret_cast<const vfloat4*>(x + xbase + k * cstep + 4));
    }
#pragma unroll
    for (int k = 0; k < 4; ++k) {
        vfloat4 o0 = { xv[2*k].x   * att[0], xv[2*k].y   * att[1],
                       xv[2*k].z   * att[2], xv[2*k].w   * att[3] };
        vfloat4 o1 = { xv[2*k+1].x * att[4], xv[2*k+1].y * att[5],
                       xv[2*k+1].z * att[6], xv[2*k+1].w * att[7] };
        __builtin_nontemporal_store(o0, reinterpret_cast<vfloat4*>(out + xbase + k * cstep));
        __builtin_nontemporal_store(o1, reinterpret_cast<vfloat4*>(out + xbase + k * cstep + 4));
    }
}

extern "C" void kernel_launch(void* const* d_in, const int* in_sizes, int n_in,
                              void* d_out, int out_size, void* d_ws, size_t ws_size,
                              hipStream_t stream) {
    const float* x  = (const float*)d_in[0];
    const float* cw = (const float*)d_in[1];
    const float* g1 = (const float*)d_in[2];
    const float* b1 = (const float*)d_in[3];
    const float* g2 = (const float*)d_in[4];
    const float* b2 = (const float*)d_in[5];
    float* out = (float*)d_out;

    char* ws = (char*)d_ws;
    float* feat    = (float*)ws;                              // 4 MiB: [B][2][HW]
    float* convout = (float*)(ws + 4u * 1024 * 1024);         // 2 MiB: [B][HW]
    float* pp      = (float*)(ws + 6u * 1024 * 1024);         // 16 KiB: BN1 partials [4][1024]
    float* bn2     = (float*)(ws + 6u * 1024 * 1024 + 65536); // 2 floats: BN2 accumulators

    // No memset dispatch: pp fully rewritten by k_reduce each call; bn2 zeroed
    // by k_reduce block 0 before k_conv's atomics (stream-ordered).
    k_reduce<<<1024, 256, 0, stream>>>(x, feat, pp, bn2);
    k_conv  <<<512,  256, 0, stream>>>(feat, cw, g1, b1, pp, convout, bn2);
    k_apply <<<8192, 256, 0, stream>>>(x, convout, g2, b2, bn2, out);
}

// Round 13
// 170.459 us; speedup vs baseline: 1.0696x; 1.0696x over previous
//
#include <hip/hip_runtime.h>
#include <math.h>

#define B_    32
#define C_    128
#define HW_   16384          // 128*128
#define NPIX  524288         // B_*HW_
#define EPSF  1e-5f

typedef float vfloat4 __attribute__((ext_vector_type(4)));  // native vec for nontemporal builtins

__device__ __forceinline__ float wave_sum(float v) {
#pragma unroll
    for (int off = 32; off > 0; off >>= 1) v += __shfl_down(v, off, 64);
    return v;
}

// Kernel 1 (R10 exact): per-pixel channel mean/max over C=128, channel loop
// split 2-way across wave halves, combine via shfl_xor 32. Emits feat[B][2][HW].
// BN1 stats as deterministic per-block partials pp[4][1024]; block 0 zeroes
// the BN2 accumulators for k_conv.
__global__ __launch_bounds__(256) void k_reduce(const float* __restrict__ x,
                                                float* __restrict__ feat,
                                                float* __restrict__ pp,
                                                float* __restrict__ bn2) {
    if (blockIdx.x == 0 && threadIdx.x < 2) bn2[threadIdx.x] = 0.f;  // ws not re-poisoned; zero every call

    int lane = threadIdx.x & 63, wid = threadIdx.x >> 6;
    int pg   = (blockIdx.x * 4 + wid) * 32 + (lane & 31);  // float4-pixel group, 131072 total
    int b    = pg >> 12;
    int hw   = (pg & 4095) << 2;
    int ch0  = (lane >> 5) * 64;                           // 0 or 64

    const float4* xp = reinterpret_cast<const float4*>(
        x + (size_t)b * C_ * HW_ + (size_t)ch0 * HW_ + hw);
    float4 s = make_float4(0.f, 0.f, 0.f, 0.f);
    float4 m = make_float4(-INFINITY, -INFINITY, -INFINITY, -INFINITY);
#pragma unroll 8
    for (int c = 0; c < 64; ++c) {
        float4 v = xp[(size_t)c * (HW_ / 4)];
        s.x += v.x; s.y += v.y; s.z += v.z; s.w += v.w;
        m.x = fmaxf(m.x, v.x); m.y = fmaxf(m.y, v.y);
        m.z = fmaxf(m.z, v.z); m.w = fmaxf(m.w, v.w);
    }
    s.x += __shfl_xor(s.x, 32, 64); s.y += __shfl_xor(s.y, 32, 64);
    s.z += __shfl_xor(s.z, 32, 64); s.w += __shfl_xor(s.w, 32, 64);
    m.x = fmaxf(m.x, __shfl_xor(m.x, 32, 64)); m.y = fmaxf(m.y, __shfl_xor(m.y, 32, 64));
    m.z = fmaxf(m.z, __shfl_xor(m.z, 32, 64)); m.w = fmaxf(m.w, __shfl_xor(m.w, 32, 64));

    const float inv = 1.0f / 128.0f;
    float4 a = make_float4(s.x * inv, s.y * inv, s.z * inv, s.w * inv);
    float* fb = feat + (size_t)b * 2 * HW_ + hw;
    if (lane < 32) *reinterpret_cast<float4*>(fb)       = a;   // avg plane
    else           *reinterpret_cast<float4*>(fb + HW_) = m;   // max plane

    float vals[4];
    vals[0] = a.x + a.y + a.z + a.w;
    vals[1] = a.x*a.x + a.y*a.y + a.z*a.z + a.w*a.w;
    vals[2] = m.x + m.y + m.z + m.w;
    vals[3] = m.x*m.x + m.y*m.y + m.z*m.z + m.w*m.w;

    __shared__ float red[4];
#pragma unroll
    for (int i = 0; i < 4; ++i) {        // halves duplicate -> 0.5x
        float v = wave_sum(vals[i]);
        if (lane == 0) red[wid] = v;
        __syncthreads();
        if (threadIdx.x == 0)
            pp[i * 1024 + blockIdx.x] = 0.5f * (red[0] + red[1] + red[2] + red[3]);
        __syncthreads();
    }
}

// Kernel 2 (R10 exact): prologue reduces the 4x1024 BN1 partials per block,
// then BN1-affine-fused 7x7x2 conv (OOB = 0 post-BN), 4 output pixels/thread
// with row-reuse. BN2 stats via atomics into bn2[2].
__global__ __launch_bounds__(256) void k_conv(const float* __restrict__ feat,
                                              const float* __restrict__ cw,
                                              const float* __restrict__ g1,
                                              const float* __restrict__ be1,
                                              const float* __restrict__ pp,
                                              float* __restrict__ convout,
                                              float* __restrict__ bn2) {
    __shared__ float w_s[98];
    __shared__ float sc_s[2], sh_s[2];
    __shared__ float red4[4][4];
    int lane = threadIdx.x & 63, wid = threadIdx.x >> 6;

    if (threadIdx.x < 98) w_s[threadIdx.x] = cw[threadIdx.x];
#pragma unroll
    for (int i = 0; i < 4; ++i) {
        const float* p = pp + i * 1024 + threadIdx.x;
        float a = p[0] + p[256] + p[512] + p[768];
        a = wave_sum(a);
        if (lane == 0) red4[i][wid] = a;
    }
    __syncthreads();
    if (threadIdx.x < 2) {
        const float invn = 1.0f / (float)NPIX;
        int c = threadIdx.x;
        float S = red4[2*c][0] + red4[2*c][1] + red4[2*c][2] + red4[2*c][3];
        float Q = red4[2*c+1][0] + red4[2*c+1][1] + red4[2*c+1][2] + red4[2*c+1][3];
        float mean = S * invn;
        float var  = Q * invn - mean * mean;
        float sc   = g1[c] / sqrtf(var + EPSF);
        sc_s[c] = sc;
        sh_s[c] = be1[c] - mean * sc;
    }
    __syncthreads();

    int t  = blockIdx.x * 256 + threadIdx.x;   // 131072 threads, 4 pixels each
    int b  = t >> 12;
    int pg = t & 4095;
    int h  = pg >> 5;
    int w4 = (pg & 31) << 2;                   // output col base (0,4,...,124)
    const float* fb = feat + (size_t)b * 2 * HW_;

    float acc0 = 0.f, acc1 = 0.f, acc2 = 0.f, acc3 = 0.f;
#pragma unroll
    for (int c = 0; c < 2; ++c) {
        float sc = sc_s[c], sh = sh_s[c];
        const float* fc = fb + c * HW_;
#pragma unroll
        for (int kh = 0; kh < 7; ++kh) {
            int hh = h + kh - 3;
            if ((unsigned)hh >= 128u) continue;
            const float* row = fc + hh * 128;
            float v[10];
#pragma unroll
            for (int i = 0; i < 10; ++i) {
                int ww = w4 - 3 + i;
                v[i] = ((unsigned)ww < 128u) ? row[ww] * sc + sh : 0.f;
            }
#pragma unroll
            for (int kw = 0; kw < 7; ++kw) {
                float wt = w_s[c * 49 + kh * 7 + kw];
                acc0 += v[kw]     * wt;
                acc1 += v[kw + 1] * wt;
                acc2 += v[kw + 2] * wt;
                acc3 += v[kw + 3] * wt;
            }
        }
    }
    *reinterpret_cast<float4*>(convout + (size_t)b * HW_ + h * 128 + w4) =
        make_float4(acc0, acc1, acc2, acc3);

    __shared__ float red[4];
    float v = wave_sum(acc0 + acc1 + acc2 + acc3);
    if (lane == 0) red[wid] = v;
    __syncthreads();
    if (threadIdx.x == 0) atomicAdd(bn2 + 0, red[0] + red[1] + red[2] + red[3]);
    __syncthreads();
    v = wave_sum(acc0*acc0 + acc1*acc1 + acc2*acc2 + acc3*acc3);
    if (lane == 0) red[wid] = v;
    __syncthreads();
    if (threadIdx.x == 0) atomicAdd(bn2 + 1, red[0] + red[1] + red[2] + red[3]);
}

// Kernel 3 (R11 exact, best known): att = sigmoid(BN2(conv)); out = att * x.
// 4-way channel ILP — each thread handles c = clo, clo+32, clo+64, clo+96 of
// its (b,hw): 4 independent nt-load/nt-store pairs in flight, one convout
// read + one sigmoid quad per 4 channels. Reversed block order.
__global__ __launch_bounds__(256) void k_apply(const float* __restrict__ x,
                                               const float* __restrict__ convout,
                                               const float* __restrict__ g2,
                                               const float* __restrict__ be2,
                                               const float* __restrict__ bn2,
                                               float* __restrict__ out) {
    int t   = (gridDim.x - 1 - blockIdx.x) * 256 + threadIdx.x;  // 4,194,304 threads
    int hw  = (t & 4095) << 2;
    int clo = (t >> 12) & 31;
    int b   = t >> 17;

    const float invn = 1.0f / (float)NPIX;
    float mean = bn2[0] * invn;
    float var  = bn2[1] * invn - mean * mean;
    float s    = g2[0] / sqrtf(var + EPSF);
    float sh   = be2[0] - mean * s;

    float4 cv = *reinterpret_cast<const float4*>(convout + (size_t)b * HW_ + hw);
    float att0 = 1.f / (1.f + __expf(-(cv.x * s + sh)));
    float att1 = 1.f / (1.f + __expf(-(cv.y * s + sh)));
    float att2 = 1.f / (1.f + __expf(-(cv.z * s + sh)));
    float att3 = 1.f / (1.f + __expf(-(cv.w * s + sh)));

    size_t xbase = ((size_t)(b * 128 + clo)) * HW_ + hw;
    const size_t cstep = (size_t)32 * HW_;
    vfloat4 xv[4];
#pragma unroll
    for (int k = 0; k < 4; ++k)
        xv[k] = __builtin_nontemporal_load(
            reinterpret_cast<const vfloat4*>(x + xbase + k * cstep));
#pragma unroll
    for (int k = 0; k < 4; ++k) {
        vfloat4 o = { xv[k].x * att0, xv[k].y * att1, xv[k].z * att2, xv[k].w * att3 };
        __builtin_nontemporal_store(o, reinterpret_cast<vfloat4*>(out + xbase + k * cstep));
    }
}

extern "C" void kernel_launch(void* const* d_in, const int* in_sizes, int n_in,
                              void* d_out, int out_size, void* d_ws, size_t ws_size,
                              hipStream_t stream) {
    const float* x  = (const float*)d_in[0];
    const float* cw = (const float*)d_in[1];
    const float* g1 = (const float*)d_in[2];
    const float* b1 = (const float*)d_in[3];
    const float* g2 = (const float*)d_in[4];
    const float* b2 = (const float*)d_in[5];
    float* out = (float*)d_out;

    char* ws = (char*)d_ws;
    float* feat    = (float*)ws;                              // 4 MiB: [B][2][HW]
    float* convout = (float*)(ws + 4u * 1024 * 1024);         // 2 MiB: [B][HW]
    float* pp      = (float*)(ws + 6u * 1024 * 1024);         // 16 KiB: BN1 partials [4][1024]
    float* bn2     = (float*)(ws + 6u * 1024 * 1024 + 65536); // 2 floats: BN2 accumulators

    // No memset dispatch: pp fully rewritten by k_reduce each call; bn2 zeroed
    // by k_reduce block 0 before k_conv's atomics (stream-ordered).
    k_reduce<<<1024,  256, 0, stream>>>(x, feat, pp, bn2);
    k_conv  <<<512,   256, 0, stream>>>(feat, cw, g1, b1, pp, convout, bn2);
    k_apply <<<16384, 256, 0, stream>>>(x, convout, g2, b2, bn2, out);
}